// Round 10
// baseline (203.730 us; speedup 1.0000x reference)
//
#include <hip/hip_runtime.h>
#include <math.h>

// Problem constants (from reference)
#define BB 4
#define TT 2048
#define CC 48
#define DD 512
#define LL 16
#define NTR 15
#define NCAND 45
#define WINLEN 19   // int(T/L*0.15)
#define CSW 15
#define CCHALF 7

static __device__ __forceinline__ float wave_reduce_sum(float v) {
    for (int off = 32; off; off >>= 1) v += __shfl_down(v, off);
    return v;
}

// DPP max step
#define DPPMAX(x, ctrl) fmaxf((x), __int_as_float(__builtin_amdgcn_update_dpp( \
    __float_as_int(x), __float_as_int(x), (ctrl), 0xF, 0xF, false)))

// ---------------- Kernel 1: boundary (JS) score + center lse ----------------
// Computes the 9 window lse's inline (k_lse node eliminated); writes lse[row]
// for the center row so k_dp can consume it.
__global__ __launch_bounds__(64) void k_score(const float* __restrict__ fr,
                                              float* __restrict__ lse,
                                              float* __restrict__ score) {
    int row = blockIdx.x;
    int b = row / TT, t = row % TT;
    __shared__ float sp[9][CC];
    __shared__ float slp[9][CC];
    __shared__ float lse_s[9];
    int tid = threadIdx.x;
    // stage raw logits (0 for OOB rows)
    for (int idx = tid; idx < 9 * CC; idx += 64) {
        int i = idx / CC, c = idx - (idx / CC) * CC;
        int r = t - 4 + i;
        sp[i][c] = (r >= 0 && r < TT) ? fr[((size_t)b * TT + r) * CC + c] : 0.f;
    }
    __syncthreads();
    // per-row lse (single wave, 9 sequential reduces)
    for (int i = 0; i < 9; ++i) {
        int r = t - 4 + i;
        bool valid = (r >= 0 && r < TT);
        float xv = (tid < CC && valid) ? sp[i][tid] : -INFINITY;
        float m = xv;
        for (int off = 32; off; off >>= 1) m = fmaxf(m, __shfl_down(m, off));
        m = __shfl(m, 0);
        float e = (tid < CC && valid) ? __expf(xv - m) : 0.f;
        float s = wave_reduce_sum(e);
        if (tid == 0) lse_s[i] = valid ? (m + __logf(s)) : 0.f;
    }
    __syncthreads();
    if (tid == 0) lse[row] = lse_s[4];   // center row
    // convert raw x -> p, logp in place (each element owned by one thread)
    for (int idx = tid; idx < 9 * CC; idx += 64) {
        int i = idx / CC, c = idx - (idx / CC) * CC;
        int r = t - 4 + i;
        float lv = 0.f, pv = 0.f;
        if (r >= 0 && r < TT) { lv = sp[i][c] - lse_s[i]; pv = __expf(lv); }
        slp[i][c] = lv;
        sp[i][c] = pv;
    }
    __syncthreads();
    float acc = 0.f;
    for (int idx = tid; idx < 4 * CC; idx += 64) {
        int i = idx / CC, c = idx - (idx / CC) * CC;
        acc += -2.f * sp[i][c] * slp[i][c];
    }
    for (int item = tid; item < 36 * CC; item += 64) {
        int pidx = item / CC, c = item - pidx * CC;
        int i = 0, rem = pidx;
        while (rem >= 8 - i) { rem -= 8 - i; ++i; }
        int j = i + 1 + rem;
        float wgt = ((i < 4) == (j < 4)) ? 1.f : -1.f;
        float pi = sp[i][c], pj = sp[j][c];
        float logm = __logf(0.5f * (pi + pj) + 1e-32f);
        acc -= wgt * (pi + pj) * logm;
    }
    acc = wave_reduce_sum(acc);
    if (tid == 0) {
        const float SC = -2.0f / (81.0f * 0.6931471805599453f);
        score[row] = (t == 0) ? -INFINITY : SC * acc;
    }
}

// ---------------- Kernel 2: greedy pick, single wave, register-resident ----------------
__global__ __launch_bounds__(64) void k_pick(const float* __restrict__ score,
                                             int* __restrict__ cand,
                                             float* __restrict__ backup) {
    int b = blockIdx.x;
    int lane = threadIdx.x;
    __shared__ int cl[NCAND];
    float v[32];
    {
        const float4* sp4 = (const float4*)(score + (size_t)b * TT + (lane << 5));
        #pragma unroll
        for (int q = 0; q < 8; ++q) {
            float4 x = sp4[q];
            v[q * 4 + 0] = x.x; v[q * 4 + 1] = x.y;
            v[q * 4 + 2] = x.z; v[q * 4 + 3] = x.w;
        }
    }
    int base = lane << 5;
    for (int it = 0; it < NCAND; ++it) {
        // in-lane argmax, first index wins ties (descending k, >=)
        float best = -INFINITY; int bi = 0;
        #pragma unroll
        for (int k = 31; k >= 0; --k)
            if (v[k] >= best) { best = v[k]; bi = k; }
        // cross-lane max via DPP
        float m = best;
        m = DPPMAX(m, 0x111); m = DPPMAX(m, 0x112);
        m = DPPMAX(m, 0x114); m = DPPMAX(m, 0x118);
        m = DPPMAX(m, 0x142); m = DPPMAX(m, 0x143);
        float gmax = __int_as_float(__builtin_amdgcn_readlane(__float_as_int(m), 63));
        unsigned long long ball = __ballot(best == gmax);
        int sl = (int)(__ffsll((long long)ball) - 1);
        int mp = __builtin_amdgcn_readlane(base + bi, sl);
        if (lane == 0) cl[it] = mp;
        // suppress [mp-WINLEN, mp+WINLEN] in this lane's chunk via bitmask
        int llo = mp - WINLEN - base;
        int lhi = mp + WINLEN - base;
        unsigned lowm = (llo <= 0) ? 0xffffffffu : ((llo >= 32) ? 0u : ~((1u << llo) - 1u));
        unsigned him  = (lhi >= 31) ? 0xffffffffu : ((lhi < 0) ? 0u : ((2u << lhi) - 1u));
        unsigned wm = lowm & him;
        #pragma unroll
        for (int k = 0; k < 32; ++k)
            if (wm & (1u << k)) v[k] = -INFINITY;
    }
    __syncthreads();
    // rank-based parallel sort (positions distinct)
    if (lane < NCAND) {
        int my = cl[lane];
        int rank = 0;
        for (int i = 0; i < NCAND; ++i) rank += (cl[i] < my) ? 1 : 0;
        cand[b * 64 + rank] = my;
        backup[b * 64 + rank] = score[(size_t)b * TT + my];
    }
}

// ---------------- Kernel 3: cls (LDS-staged window) + DP + rank + frCE + la-zero ----------------
__global__ __launch_bounds__(256) void k_dp(const float* __restrict__ fr,
                                            const float* __restrict__ lse,
                                            const int* __restrict__ cand,
                                            const float* __restrict__ backup,
                                            const int* __restrict__ transcript,
                                            int* __restrict__ labels_out,
                                            int* __restrict__ rowmap,
                                            float* __restrict__ fr_part,
                                            float* __restrict__ la) {
    int b = blockIdx.x;
    __shared__ float win[NCAND][CSW][LL + 1];   // pad 17: conflict-free cost reads (~45.9 KB)
    __shared__ float cost[NTR][NCAND];
    __shared__ int tr_s[LL];
    __shared__ int cand_s[NCAND];
    __shared__ float backup_s[NCAND];
    __shared__ signed char dir_mat[NCAND][32];
    __shared__ int bdy_s[NTR];
    __shared__ int rank_s[LL];
    __shared__ float redf[4];
    int tid = threadIdx.x;
    int wave = tid >> 6, lane = tid & 63;
    if (tid < LL) tr_s[tid] = transcript[b * LL + tid];
    if (tid < NCAND) {
        cand_s[tid] = cand[b * 64 + tid];
        backup_s[tid] = backup[b * 64 + tid];
    }

    // zero la for this batch (consumed later by k_la atomics)
    {
        float4 z = {0.f, 0.f, 0.f, 0.f};
        float4* lz = (float4*)(la + (size_t)b * LL * DD);
        #pragma unroll
        for (int i = 0; i < LL * DD / 4 / 256; ++i) lz[i * 256 + tid] = z;
    }
    __syncthreads();

    // ---- stage p for the 16 transcript channels over each candidate window ----
    // win[ii][k][m] = softmax_p(row cand[ii]-7+k, channel tr[m]); 10800 loads, batch-issued
    for (int e = tid; e < NCAND * CSW * LL; e += 256) {
        int ii = e / (CSW * LL);
        int rem = e - ii * (CSW * LL);
        int k = rem >> 4;
        int m = rem & 15;
        int r = cand_s[ii] - CCHALF + k;
        float p = 0.f;
        if (r >= 0 && r < TT) {
            size_t ro = (size_t)b * TT + r;
            p = __expf(fr[ro * CC + tr_s[m]] - lse[ro]);
        }
        win[ii][k][m] = p;
    }
    __syncthreads();

    // ---- cls cost from LDS only ----
    for (int e = tid; e < NTR * NCAND; e += 256) {
        int j = e / NCAND, ii = e - (e / NCAND) * NCAND;
        float sum = 0.f;
        #pragma unroll
        for (int k = 0; k < CSW; ++k)
            sum += ((k < CCHALF) ? 1.f : -1.f) * (win[ii][k][j] - win[ii][k][j + 1]);
        cost[j][ii] = -(sum / 30.f + backup_s[ii]);
    }
    __syncthreads();

    // ---- DP (wave 0, state j = lane j, W=31) ----
    if (tid < 64) {
        float prev = INFINITY;
        if (tid == 0) prev = 0.f;
        if (tid == 1) prev = cost[0][0];
        if (tid < 31) dir_mat[0][tid] = (tid == 1) ? (signed char)1 : (signed char)0;
        for (int ii = 1; ii < NCAND; ++ii) {
            float dm1 = __shfl_up(prev, 1); if (tid < 1) dm1 = INFINITY;
            float dm2 = __shfl_up(prev, 2); if (tid < 2) dm2 = INFINITY;
            int trat = tid >> 1; if (trat > NTR - 1) trat = NTR - 1;
            float c_at = cost[trat][ii];
            float ev = fminf(prev, dm1);
            int ed = (prev < dm1) ? 0 : 1;
            float ov = c_at + fminf(dm1, dm2);
            int od = (dm1 < dm2) ? 1 : 2;
            float nv; int nd;
            if (tid >= 2) {
                if ((tid & 1) == 0) { nv = ev; nd = ed; }
                else { nv = ov; nd = od; }
            } else { nv = INFINITY; nd = 0; }
            if (tid == 0) { nv = (ii < NCAND - NTR) ? 0.f : INFINITY; nd = 0; }
            if (tid == 1) {
                nv = (ii <= NCAND - NTR) ? cost[0][ii] : INFINITY;
                nd = (ii <= NCAND - NTR) ? 1 : 0;
            }
            prev = nv;
            if (tid < 31) dir_mat[ii][tid] = (signed char)nd;
        }
        float v29 = __shfl(prev, 29);
        float v30 = __shfl(prev, 30);
        if (tid == 0) {
            int cur = (v30 < v29) ? 30 : 29;
            for (int ii = NCAND - 1; ii >= 0; --ii) {
                if (cur & 1) bdy_s[cur >> 1] = cand_s[ii];
                cur -= (int)dir_mat[ii][cur];
            }
        }
    }
    __syncthreads();

    // ---- parallel rank (transcript values distinct) ----
    if (tid < LL) {
        int myv = tr_s[tid];
        int r2 = 0;
        #pragma unroll
        for (int l2 = 0; l2 < LL; ++l2) r2 += (tr_s[l2] < myv) ? 1 : 0;
        rank_s[tid] = r2;
        labels_out[b * LL + r2] = myv;   // sorted scatter
    }
    __syncthreads();

    // ---- fr CE partial + rowmap (pse inline) ----
    float facc = 0.f;
    for (int t = tid; t < TT; t += 256) {
        int cnt = 0;
        #pragma unroll
        for (int j = 0; j < NTR; ++j) cnt += (t >= bdy_s[j]) ? 1 : 0;
        int pv = tr_s[cnt];
        rowmap[b * TT + t] = rank_s[cnt];
        size_t ro = (size_t)b * TT + t;
        facc += lse[ro] - fr[ro * CC + pv];
    }
    facc = wave_reduce_sum(facc);
    if (lane == 0) redf[wave] = facc;
    __syncthreads();
    if (tid == 0) fr_part[b] = redf[0] + redf[1] + redf[2] + redf[3];
}

// ---------------- Kernel 4: segment feature sums, float4 tile-scatter ----------------
// 32-row tile; half-block h handles rows t0+h, t0+h+2, ... (16 rows), 128 lanes
// cover the 512-col row as float4 (fully coalesced 16B/lane).
__global__ __launch_bounds__(256) void k_la(const float* __restrict__ feat,
                                            const int* __restrict__ rowmap,
                                            float* __restrict__ la) {
    int b = blockIdx.y;
    int t0 = blockIdx.x * 32;
    int tid = threadIdx.x;
    int h = tid >> 7;          // 0/1
    int col = tid & 127;       // float4 index
    const float* frf = feat + ((size_t)b * (CC + TT) + CC) * DD;
    __shared__ int rm[32];
    if (tid < 32) rm[tid] = rowmap[b * TT + t0 + tid];
    __syncthreads();
    float4 acc = {0.f, 0.f, 0.f, 0.f};
    int cur = rm[h];
    for (int k = h; k < 32; k += 2) {
        int r = rm[k];
        if (r != cur) {   // uniform within each half-block (wave-uniform)
            float* dst = la + ((size_t)b * LL + cur) * DD + col * 4;
            atomicAdd(dst + 0, acc.x); atomicAdd(dst + 1, acc.y);
            atomicAdd(dst + 2, acc.z); atomicAdd(dst + 3, acc.w);
            acc.x = 0.f; acc.y = 0.f; acc.z = 0.f; acc.w = 0.f;
            cur = r;
        }
        float4 v = ((const float4*)(frf + (size_t)(t0 + k) * DD))[col];
        acc.x += v.x; acc.y += v.y; acc.z += v.z; acc.w += v.w;
    }
    float* dst = la + ((size_t)b * LL + cur) * DD + col * 4;
    atomicAdd(dst + 0, acc.x); atomicAdd(dst + 1, acc.y);
    atomicAdd(dst + 2, acc.z); atomicAdd(dst + 3, acc.w);
}

// ---------------- Kernel 5: glc dots per (b,c): tok row staged, 16 dots + ntk ----------------
__global__ __launch_bounds__(256) void k_glc(const float* __restrict__ feat,
                                             const float* __restrict__ la,
                                             float* __restrict__ dots,
                                             float* __restrict__ ntk) {
    int c = blockIdx.x, b = blockIdx.y;
    __shared__ float tok_s[DD];
    __shared__ float redv[4];
    int tid = threadIdx.x;
    int wave = tid >> 6, lane = tid & 63;
    const float* tr = feat + ((size_t)b * (CC + TT) + c) * DD;
    float2 tv = ((const float2*)tr)[tid];
    ((float2*)tok_s)[tid] = tv;
    float vv = tv.x * tv.x + tv.y * tv.y;
    vv = wave_reduce_sum(vv);
    if (lane == 0) redv[wave] = vv;
    __syncthreads();
    if (tid == 0)
        ntk[b * CC + c] = fmaxf(sqrtf(redv[0] + redv[1] + redv[2] + redv[3]), 1e-12f);
    for (int l = wave; l < LL; l += 4) {
        const float4* lar = (const float4*)(la + ((size_t)b * LL + l) * DD);
        const float4* ts = (const float4*)tok_s;
        float dot = 0.f;
        #pragma unroll
        for (int jj = 0; jj < 2; ++jj) {
            int j = lane + jj * 64;
            float4 a = lar[j]; float4 w = ts[j];
            dot += a.x * w.x + a.y * w.y + a.z * w.z + a.w * w.w;
        }
        dot = wave_reduce_sum(dot);
        if (lane == 0) dots[((size_t)b * LL + l) * CC + c] = dot;
    }
}

// ---------------- Kernel 6: final — per-(b,l) terms + tok BCE + combine ----------------
__global__ __launch_bounds__(256) void k_final(const float* __restrict__ tok_logit,
                                               const float* __restrict__ vid,
                                               const float* __restrict__ fr_part,
                                               const float* __restrict__ la,
                                               const float* __restrict__ dots,
                                               const float* __restrict__ ntk,
                                               const int* __restrict__ labels,
                                               float* __restrict__ out) {
    int tid = threadIdx.x;
    int wave = tid >> 6, lane = tid & 63;
    __shared__ float term_s[BB * LL];
    __shared__ float red[4];
    __shared__ float gterm;
    // 64 (b,l) jobs, 16 per wave
    for (int i = 0; i < 16; ++i) {
        int job = wave * 16 + i;
        int b = job >> 4;
        const float4* lar = (const float4*)(la + (size_t)job * DD);
        float ss = 0.f;
        #pragma unroll
        for (int jj = 0; jj < 2; ++jj) {
            float4 a = lar[lane + jj * 64];
            ss += a.x * a.x + a.y * a.y + a.z * a.z + a.w * a.w;
        }
        ss = wave_reduce_sum(ss);
        float nla = fmaxf(sqrtf(__shfl(ss, 0)), 1e-12f);
        float sim = -INFINITY;
        if (lane < CC)
            sim = dots[(size_t)job * CC + lane] * 10.0f / (nla * ntk[b * CC + lane]);
        float mx = sim;
        for (int off = 32; off; off >>= 1) mx = fmaxf(mx, __shfl_down(mx, off));
        mx = __shfl(mx, 0);
        float e = (lane < CC) ? expf(sim - mx) : 0.f;
        float se = wave_reduce_sum(e);
        se = __shfl(se, 0);
        int lab = labels[job];
        float sim_lab = __shfl(sim, lab);
        if (lane == 0) term_s[job] = (mx + logf(se)) - sim_lab;
    }
    // tok BCE
    float acc = 0.f;
    if (tid < BB * CC) {
        float x = tok_logit[tid], y = vid[tid];
        float lsp = fminf(x, 0.f) - log1pf(expf(-fabsf(x)));
        float lsn = fminf(-x, 0.f) - log1pf(expf(-fabsf(x)));
        acc = -(y * lsp + (1.f - y) * lsn);
    }
    float w = wave_reduce_sum(acc);
    if (lane == 0) red[wave] = w;
    __syncthreads();
    if (tid < 64) {
        float g = term_s[tid];
        g = wave_reduce_sum(g);
        if (tid == 0) gterm = g;
    }
    __syncthreads();
    if (tid == 0) {
        float s_tok = (red[0] + red[1] + red[2] + red[3]) / (float)(BB * CC);
        float sfr = fr_part[0] + fr_part[1] + fr_part[2] + fr_part[3];
        float s_fr = sfr / (float)(BB * TT);
        float glc = gterm / (float)(BB * LL);
        out[0] = s_tok + s_fr + 0.1f * glc;
    }
}

extern "C" void kernel_launch(void* const* d_in, const int* in_sizes, int n_in,
                              void* d_out, int out_size, void* d_ws, size_t ws_size,
                              hipStream_t stream) {
    (void)in_sizes; (void)n_in; (void)out_size; (void)ws_size;
    // input order: epoch, tok_logit, fr_logit, mask, transcript, vid_multi_hot, feat
    const float* tok_logit  = (const float*)d_in[1];
    const float* fr_logit   = (const float*)d_in[2];
    const int*   transcript = (const int*)d_in[4];
    const float* vid        = (const float*)d_in[5];
    const float* feat       = (const float*)d_in[6];

    char* ws = (char*)d_ws;
    float* lse     = (float*)(ws + 0);        // B*T (32768 B)
    float* score   = (float*)(ws + 32768);    // B*T (32768 B)
    float* la      = (float*)(ws + 65536);    // B*L*D (131072 B)
    float* dots    = (float*)(ws + 196608);   // B*L*C (12288 B)
    float* ntk     = (float*)(ws + 208896);   // B*C
    float* fr_part = (float*)(ws + 209920);   // 4
    int*   labels  = (int*)(ws + 210176);     // B*L
    int*   rowmap  = (int*)(ws + 210432);     // B*T (32768 B)
    int*   cand    = (int*)(ws + 243200);     // B*64
    float* backup  = (float*)(ws + 244224);   // B*64
    float* out     = (float*)d_out;

    k_score<<<BB * TT, 64, 0, stream>>>(fr_logit, lse, score);
    k_pick<<<BB, 64, 0, stream>>>(score, cand, backup);
    k_dp<<<BB, 256, 0, stream>>>(fr_logit, lse, cand, backup, transcript,
                                 labels, rowmap, fr_part, la);
    k_la<<<dim3(TT / 32, BB), 256, 0, stream>>>(feat, rowmap, la);
    k_glc<<<dim3(CC, BB), 256, 0, stream>>>(feat, la, dots, ntk);
    k_final<<<1, 256, 0, stream>>>(tok_logit, vid, fr_part, la, dots, ntk, labels, out);
}

// Round 11
// 189.396 us; speedup vs baseline: 1.0757x; 1.0757x over previous
//
#include <hip/hip_runtime.h>
#include <math.h>

// Problem constants (from reference)
#define BB 4
#define TT 2048
#define CC 48
#define DD 512
#define LL 16
#define NTR 15
#define NCAND 45
#define WINLEN 19   // int(T/L*0.15)
#define CSW 15
#define CCHALF 7

static __device__ __forceinline__ float wave_reduce_sum(float v) {
    for (int off = 32; off; off >>= 1) v += __shfl_down(v, off);
    return v;
}

// DPP max step
#define DPPMAX(x, ctrl) fmaxf((x), __int_as_float(__builtin_amdgcn_update_dpp( \
    __float_as_int(x), __float_as_int(x), (ctrl), 0xF, 0xF, false)))

// ---------------- Kernel 1: row log-sum-exp only ----------------
__global__ __launch_bounds__(256) void k_lse(const float* __restrict__ fr,
                                             float* __restrict__ lse) {
    int row = blockIdx.x * 4 + (threadIdx.x >> 6);   // 4 rows/block
    int lane = threadIdx.x & 63;
    float xv = (lane < CC) ? fr[(size_t)row * CC + lane] : -INFINITY;
    float m = xv;
    for (int off = 32; off; off >>= 1) m = fmaxf(m, __shfl_down(m, off));
    m = __shfl(m, 0);
    float e = (lane < CC) ? __expf(xv - m) : 0.f;
    float s = wave_reduce_sum(e);
    if (lane == 0) lse[row] = m + __logf(s);
}

// ---------------- Kernel 2: boundary (JS) score, on-the-fly softmax ----------------
__global__ __launch_bounds__(64) void k_score(const float* __restrict__ fr,
                                              const float* __restrict__ lse,
                                              float* __restrict__ score) {
    int row = blockIdx.x;
    int b = row / TT, t = row % TT;
    __shared__ float sp[9][CC];
    __shared__ float slp[9][CC];
    __shared__ float lse_s[9];
    int tid = threadIdx.x;
    if (tid < 9) {
        int r = t - 4 + tid;
        lse_s[tid] = (r >= 0 && r < TT) ? lse[b * TT + r] : 0.f;
    }
    __syncthreads();
    for (int idx = tid; idx < 9 * CC; idx += 64) {
        int i = idx / CC, c = idx - (idx / CC) * CC;
        int r = t - 4 + i;
        float pv = 0.f, lv = 0.f;
        if (r >= 0 && r < TT) {
            float x = fr[((size_t)b * TT + r) * CC + c];
            lv = x - lse_s[i];
            pv = __expf(lv);
        }
        sp[i][c] = pv;
        slp[i][c] = lv;
    }
    __syncthreads();
    float acc = 0.f;
    for (int idx = tid; idx < 4 * CC; idx += 64) {
        int i = idx / CC, c = idx - (idx / CC) * CC;
        acc += -2.f * sp[i][c] * slp[i][c];
    }
    for (int item = tid; item < 36 * CC; item += 64) {
        int pidx = item / CC, c = item - pidx * CC;
        int i = 0, rem = pidx;
        while (rem >= 8 - i) { rem -= 8 - i; ++i; }
        int j = i + 1 + rem;
        float wgt = ((i < 4) == (j < 4)) ? 1.f : -1.f;
        float pi = sp[i][c], pj = sp[j][c];
        float logm = __logf(0.5f * (pi + pj) + 1e-32f);
        acc -= wgt * (pi + pj) * logm;
    }
    acc = wave_reduce_sum(acc);
    if (tid == 0) {
        const float SC = -2.0f / (81.0f * 0.6931471805599453f);
        score[row] = (t == 0) ? -INFINITY : SC * acc;
    }
}

// ---------------- Kernel 3: greedy pick, single wave, register-resident ----------------
__global__ __launch_bounds__(64) void k_pick(const float* __restrict__ score,
                                             int* __restrict__ cand,
                                             float* __restrict__ backup) {
    int b = blockIdx.x;
    int lane = threadIdx.x;
    __shared__ float s[64 * 33];
    __shared__ int cl[NCAND];
    for (int t = lane; t < TT; t += 64) s[t + (t >> 5)] = score[(size_t)b * TT + t];
    __syncthreads();
    float v[32];
    #pragma unroll
    for (int k = 0; k < 32; ++k) v[k] = s[lane * 33 + k];   // stride-33: conflict-free
    int base = lane << 5;
    for (int it = 0; it < NCAND; ++it) {
        // in-lane argmax, first index wins ties (descending k, >=)
        float best = -INFINITY; int bi = 0;
        #pragma unroll
        for (int k = 31; k >= 0; --k)
            if (v[k] >= best) { best = v[k]; bi = k; }
        // cross-lane max via DPP
        float m = best;
        m = DPPMAX(m, 0x111); m = DPPMAX(m, 0x112);
        m = DPPMAX(m, 0x114); m = DPPMAX(m, 0x118);
        m = DPPMAX(m, 0x142); m = DPPMAX(m, 0x143);
        float gmax = __int_as_float(__builtin_amdgcn_readlane(__float_as_int(m), 63));
        unsigned long long ball = __ballot(best == gmax);
        int sl = (int)(__ffsll((long long)ball) - 1);
        int mp = __builtin_amdgcn_readlane(base + bi, sl);
        if (lane == 0) cl[it] = mp;
        // suppress [mp-WINLEN, mp+WINLEN] in this lane's chunk via bitmask
        int llo = mp - WINLEN - base;
        int lhi = mp + WINLEN - base;
        unsigned lowm = (llo <= 0) ? 0xffffffffu : ((llo >= 32) ? 0u : ~((1u << llo) - 1u));
        unsigned him  = (lhi >= 31) ? 0xffffffffu : ((lhi < 0) ? 0u : ((2u << lhi) - 1u));
        unsigned wm = lowm & him;
        #pragma unroll
        for (int k = 0; k < 32; ++k)
            if (wm & (1u << k)) v[k] = -INFINITY;
    }
    __syncthreads();
    // rank-based parallel sort (positions distinct); backup from untouched LDS copy
    if (lane < NCAND) {
        int my = cl[lane];
        int rank = 0;
        for (int i = 0; i < NCAND; ++i) rank += (cl[i] < my) ? 1 : 0;
        cand[b * 64 + rank] = my;
        backup[b * 64 + rank] = s[my + (my >> 5)];
    }
}

// ---------------- Kernel 4: cls (LDS-staged window) + DP + rank + frCE + la-zero ----------------
__global__ __launch_bounds__(256) void k_dp(const float* __restrict__ fr,
                                            const float* __restrict__ lse,
                                            const int* __restrict__ cand,
                                            const float* __restrict__ backup,
                                            const int* __restrict__ transcript,
                                            int* __restrict__ labels_out,
                                            int* __restrict__ rowmap,
                                            float* __restrict__ fr_part,
                                            float* __restrict__ la) {
    int b = blockIdx.x;
    __shared__ float win[NCAND][CSW][LL + 1];   // pad 17: conflict-free cost reads (~45.9 KB)
    __shared__ float cost[NTR][NCAND];
    __shared__ int tr_s[LL];
    __shared__ int cand_s[NCAND];
    __shared__ float backup_s[NCAND];
    __shared__ signed char dir_mat[NCAND][32];
    __shared__ int bdy_s[NTR];
    __shared__ int rank_s[LL];
    __shared__ float redf[4];
    int tid = threadIdx.x;
    int wave = tid >> 6, lane = tid & 63;
    if (tid < LL) tr_s[tid] = transcript[b * LL + tid];
    if (tid < NCAND) {
        cand_s[tid] = cand[b * 64 + tid];
        backup_s[tid] = backup[b * 64 + tid];
    }

    // zero la for this batch (consumed later by k_la atomics)
    {
        float4 z = {0.f, 0.f, 0.f, 0.f};
        float4* lz = (float4*)(la + (size_t)b * LL * DD);
        #pragma unroll
        for (int i = 0; i < LL * DD / 4 / 256; ++i) lz[i * 256 + tid] = z;
    }
    __syncthreads();

    // ---- stage p for the 16 transcript channels over each candidate window ----
    // win[ii][k][m] = softmax_p(row cand[ii]-7+k, channel tr[m]); 10800 loads, batch-issued
    for (int e = tid; e < NCAND * CSW * LL; e += 256) {
        int ii = e / (CSW * LL);
        int rem = e - ii * (CSW * LL);
        int k = rem >> 4;
        int m = rem & 15;
        int r = cand_s[ii] - CCHALF + k;
        float p = 0.f;
        if (r >= 0 && r < TT) {
            size_t ro = (size_t)b * TT + r;
            p = __expf(fr[ro * CC + tr_s[m]] - lse[ro]);
        }
        win[ii][k][m] = p;
    }
    __syncthreads();

    // ---- cls cost from LDS only ----
    for (int e = tid; e < NTR * NCAND; e += 256) {
        int j = e / NCAND, ii = e - (e / NCAND) * NCAND;
        float sum = 0.f;
        #pragma unroll
        for (int k = 0; k < CSW; ++k)
            sum += ((k < CCHALF) ? 1.f : -1.f) * (win[ii][k][j] - win[ii][k][j + 1]);
        cost[j][ii] = -(sum / 30.f + backup_s[ii]);
    }
    __syncthreads();

    // ---- DP (wave 0, state j = lane j, W=31) ----
    if (tid < 64) {
        float prev = INFINITY;
        if (tid == 0) prev = 0.f;
        if (tid == 1) prev = cost[0][0];
        if (tid < 31) dir_mat[0][tid] = (tid == 1) ? (signed char)1 : (signed char)0;
        for (int ii = 1; ii < NCAND; ++ii) {
            float dm1 = __shfl_up(prev, 1); if (tid < 1) dm1 = INFINITY;
            float dm2 = __shfl_up(prev, 2); if (tid < 2) dm2 = INFINITY;
            int trat = tid >> 1; if (trat > NTR - 1) trat = NTR - 1;
            float c_at = cost[trat][ii];
            float ev = fminf(prev, dm1);
            int ed = (prev < dm1) ? 0 : 1;
            float ov = c_at + fminf(dm1, dm2);
            int od = (dm1 < dm2) ? 1 : 2;
            float nv; int nd;
            if (tid >= 2) {
                if ((tid & 1) == 0) { nv = ev; nd = ed; }
                else { nv = ov; nd = od; }
            } else { nv = INFINITY; nd = 0; }
            if (tid == 0) { nv = (ii < NCAND - NTR) ? 0.f : INFINITY; nd = 0; }
            if (tid == 1) {
                nv = (ii <= NCAND - NTR) ? cost[0][ii] : INFINITY;
                nd = (ii <= NCAND - NTR) ? 1 : 0;
            }
            prev = nv;
            if (tid < 31) dir_mat[ii][tid] = (signed char)nd;
        }
        float v29 = __shfl(prev, 29);
        float v30 = __shfl(prev, 30);
        if (tid == 0) {
            int cur = (v30 < v29) ? 30 : 29;
            for (int ii = NCAND - 1; ii >= 0; --ii) {
                if (cur & 1) bdy_s[cur >> 1] = cand_s[ii];
                cur -= (int)dir_mat[ii][cur];
            }
        }
    }
    __syncthreads();

    // ---- parallel rank (transcript values distinct) ----
    if (tid < LL) {
        int myv = tr_s[tid];
        int r2 = 0;
        #pragma unroll
        for (int l2 = 0; l2 < LL; ++l2) r2 += (tr_s[l2] < myv) ? 1 : 0;
        rank_s[tid] = r2;
        labels_out[b * LL + r2] = myv;   // sorted scatter
    }
    __syncthreads();

    // ---- fr CE partial + rowmap (pse inline) ----
    float facc = 0.f;
    for (int t = tid; t < TT; t += 256) {
        int cnt = 0;
        #pragma unroll
        for (int j = 0; j < NTR; ++j) cnt += (t >= bdy_s[j]) ? 1 : 0;
        int pv = tr_s[cnt];
        rowmap[b * TT + t] = rank_s[cnt];
        size_t ro = (size_t)b * TT + t;
        facc += lse[ro] - fr[ro * CC + pv];
    }
    facc = wave_reduce_sum(facc);
    if (lane == 0) redf[wave] = facc;
    __syncthreads();
    if (tid == 0) fr_part[b] = redf[0] + redf[1] + redf[2] + redf[3];
}

// ---------------- Kernel 5: segment feature sums, tile-scatter (atomics) ----------------
__global__ __launch_bounds__(256) void k_la(const float* __restrict__ feat,
                                            const int* __restrict__ rowmap,
                                            float* __restrict__ la) {
    int b = blockIdx.y;
    int t0 = blockIdx.x * 32;
    int tid = threadIdx.x;
    const float* frf = feat + ((size_t)b * (CC + TT) + CC) * DD;
    __shared__ int rm[32];
    if (tid < 32) rm[tid] = rowmap[b * TT + t0 + tid];
    __syncthreads();
    float ax = 0.f, ay = 0.f;
    int cur = rm[0];
    for (int k = 0; k < 32; ++k) {
        int r = rm[k];
        if (r != cur) {   // block-uniform branch
            float* dst = la + ((size_t)b * LL + cur) * DD + tid * 2;
            atomicAdd(dst, ax);
            atomicAdd(dst + 1, ay);
            ax = 0.f; ay = 0.f; cur = r;
        }
        const float2* p = (const float2*)(frf + (size_t)(t0 + k) * DD);
        float2 v = p[tid];
        ax += v.x; ay += v.y;
    }
    float* dst = la + ((size_t)b * LL + cur) * DD + tid * 2;
    atomicAdd(dst, ax);
    atomicAdd(dst + 1, ay);
}

// ---------------- Kernel 6: glc dots per (b,c): tok row staged, 16 dots + ntk ----------------
__global__ __launch_bounds__(256) void k_glc(const float* __restrict__ feat,
                                             const float* __restrict__ la,
                                             float* __restrict__ dots,
                                             float* __restrict__ ntk) {
    int c = blockIdx.x, b = blockIdx.y;
    __shared__ float tok_s[DD];
    __shared__ float redv[4];
    int tid = threadIdx.x;
    int wave = tid >> 6, lane = tid & 63;
    const float* tr = feat + ((size_t)b * (CC + TT) + c) * DD;
    float2 tv = ((const float2*)tr)[tid];
    ((float2*)tok_s)[tid] = tv;
    float vv = tv.x * tv.x + tv.y * tv.y;
    vv = wave_reduce_sum(vv);
    if (lane == 0) redv[wave] = vv;
    __syncthreads();
    if (tid == 0)
        ntk[b * CC + c] = fmaxf(sqrtf(redv[0] + redv[1] + redv[2] + redv[3]), 1e-12f);
    for (int l = wave; l < LL; l += 4) {
        const float4* lar = (const float4*)(la + ((size_t)b * LL + l) * DD);
        const float4* ts = (const float4*)tok_s;
        float dot = 0.f;
        #pragma unroll
        for (int jj = 0; jj < 2; ++jj) {
            int j = lane + jj * 64;
            float4 a = lar[j]; float4 w = ts[j];
            dot += a.x * w.x + a.y * w.y + a.z * w.z + a.w * w.w;
        }
        dot = wave_reduce_sum(dot);
        if (lane == 0) dots[((size_t)b * LL + l) * CC + c] = dot;
    }
}

// ---------------- Kernel 7: final — per-(b,l) terms + tok BCE + combine ----------------
__global__ __launch_bounds__(256) void k_final(const float* __restrict__ tok_logit,
                                               const float* __restrict__ vid,
                                               const float* __restrict__ fr_part,
                                               const float* __restrict__ la,
                                               const float* __restrict__ dots,
                                               const float* __restrict__ ntk,
                                               const int* __restrict__ labels,
                                               float* __restrict__ out) {
    int tid = threadIdx.x;
    int wave = tid >> 6, lane = tid & 63;
    __shared__ float term_s[BB * LL];
    __shared__ float red[4];
    __shared__ float gterm;
    // 64 (b,l) jobs, 16 per wave
    for (int i = 0; i < 16; ++i) {
        int job = wave * 16 + i;
        int b = job >> 4;
        const float4* lar = (const float4*)(la + (size_t)job * DD);
        float ss = 0.f;
        #pragma unroll
        for (int jj = 0; jj < 2; ++jj) {
            float4 a = lar[lane + jj * 64];
            ss += a.x * a.x + a.y * a.y + a.z * a.z + a.w * a.w;
        }
        ss = wave_reduce_sum(ss);
        float nla = fmaxf(sqrtf(__shfl(ss, 0)), 1e-12f);
        float sim = -INFINITY;
        if (lane < CC)
            sim = dots[(size_t)job * CC + lane] * 10.0f / (nla * ntk[b * CC + lane]);
        float mx = sim;
        for (int off = 32; off; off >>= 1) mx = fmaxf(mx, __shfl_down(mx, off));
        mx = __shfl(mx, 0);
        float e = (lane < CC) ? expf(sim - mx) : 0.f;
        float se = wave_reduce_sum(e);
        se = __shfl(se, 0);
        int lab = labels[job];
        float sim_lab = __shfl(sim, lab);
        if (lane == 0) term_s[job] = (mx + logf(se)) - sim_lab;
    }
    // tok BCE
    float acc = 0.f;
    if (tid < BB * CC) {
        float x = tok_logit[tid], y = vid[tid];
        float lsp = fminf(x, 0.f) - log1pf(expf(-fabsf(x)));
        float lsn = fminf(-x, 0.f) - log1pf(expf(-fabsf(x)));
        acc = -(y * lsp + (1.f - y) * lsn);
    }
    float w = wave_reduce_sum(acc);
    if (lane == 0) red[wave] = w;
    __syncthreads();
    if (tid < 64) {
        float g = term_s[tid];
        g = wave_reduce_sum(g);
        if (tid == 0) gterm = g;
    }
    __syncthreads();
    if (tid == 0) {
        float s_tok = (red[0] + red[1] + red[2] + red[3]) / (float)(BB * CC);
        float sfr = fr_part[0] + fr_part[1] + fr_part[2] + fr_part[3];
        float s_fr = sfr / (float)(BB * TT);
        float glc = gterm / (float)(BB * LL);
        out[0] = s_tok + s_fr + 0.1f * glc;
    }
}

extern "C" void kernel_launch(void* const* d_in, const int* in_sizes, int n_in,
                              void* d_out, int out_size, void* d_ws, size_t ws_size,
                              hipStream_t stream) {
    (void)in_sizes; (void)n_in; (void)out_size; (void)ws_size;
    // input order: epoch, tok_logit, fr_logit, mask, transcript, vid_multi_hot, feat
    const float* tok_logit  = (const float*)d_in[1];
    const float* fr_logit   = (const float*)d_in[2];
    const int*   transcript = (const int*)d_in[4];
    const float* vid        = (const float*)d_in[5];
    const float* feat       = (const float*)d_in[6];

    char* ws = (char*)d_ws;
    float* lse     = (float*)(ws + 0);        // B*T (32768 B)
    float* score   = (float*)(ws + 32768);    // B*T (32768 B)
    float* la      = (float*)(ws + 65536);    // B*L*D (131072 B)
    float* dots    = (float*)(ws + 196608);   // B*L*C (12288 B)
    float* ntk     = (float*)(ws + 208896);   // B*C
    float* fr_part = (float*)(ws + 209920);   // 4
    int*   labels  = (int*)(ws + 210176);     // B*L
    int*   rowmap  = (int*)(ws + 210432);     // B*T (32768 B)
    int*   cand    = (int*)(ws + 243200);     // B*64
    float* backup  = (float*)(ws + 244224);   // B*64
    float* out     = (float*)d_out;

    k_lse<<<BB * TT / 4, 256, 0, stream>>>(fr_logit, lse);
    k_score<<<BB * TT, 64, 0, stream>>>(fr_logit, lse, score);
    k_pick<<<BB, 64, 0, stream>>>(score, cand, backup);
    k_dp<<<BB, 256, 0, stream>>>(fr_logit, lse, cand, backup, transcript,
                                 labels, rowmap, fr_part, la);
    k_la<<<dim3(TT / 32, BB), 256, 0, stream>>>(feat, rowmap, la);
    k_glc<<<dim3(CC, BB), 256, 0, stream>>>(feat, la, dots, ntk);
    k_final<<<1, 256, 0, stream>>>(tok_logit, vid, fr_part, la, dots, ntk, labels, out);
}

// Round 12
// 172.624 us; speedup vs baseline: 1.1802x; 1.0972x over previous
//
#include <hip/hip_runtime.h>
#include <math.h>

// Problem constants (from reference)
#define BB 4
#define TT 2048
#define CC 48
#define DD 512
#define LL 16
#define NTR 15
#define NCAND 45
#define WINLEN 19   // int(T/L*0.15)
#define CSW 15
#define CCHALF 7

static __device__ __forceinline__ float wave_reduce_sum(float v) {
    for (int off = 32; off; off >>= 1) v += __shfl_down(v, off);
    return v;
}

// DPP max step
#define DPPMAX(x, ctrl) fmaxf((x), __int_as_float(__builtin_amdgcn_update_dpp( \
    __float_as_int(x), __float_as_int(x), (ctrl), 0xF, 0xF, false)))

// ---------------- Kernel 1: row log-sum-exp only ----------------
__global__ __launch_bounds__(256) void k_lse(const float* __restrict__ fr,
                                             float* __restrict__ lse) {
    int row = blockIdx.x * 4 + (threadIdx.x >> 6);   // 4 rows/block
    int lane = threadIdx.x & 63;
    float xv = (lane < CC) ? fr[(size_t)row * CC + lane] : -INFINITY;
    float m = xv;
    for (int off = 32; off; off >>= 1) m = fmaxf(m, __shfl_down(m, off));
    m = __shfl(m, 0);
    float e = (lane < CC) ? __expf(xv - m) : 0.f;
    float s = wave_reduce_sum(e);
    if (lane == 0) lse[row] = m + __logf(s);
}

// ---------------- Kernel 2: boundary (JS) score, 4 t's/block (shared staging) ----------------
// Block handles t_base..t_base+3 (one t per wave). Stages 12 rows (t_base-4..t_base+7)
// once instead of 4 overlapping 9-row windows: 3x fewer global loads, 1 barrier.
__global__ __launch_bounds__(256) void k_score(const float* __restrict__ fr,
                                               const float* __restrict__ lse,
                                               float* __restrict__ score) {
    int t_base = (blockIdx.x * 4) % TT;
    int b = (blockIdx.x * 4) / TT;
    __shared__ float sp[12][CC];
    __shared__ float slp[12][CC];
    __shared__ float lse_s[12];
    int tid = threadIdx.x;
    int wave = tid >> 6, lane = tid & 63;
    if (tid < 12) {
        int r = t_base - 4 + tid;
        lse_s[tid] = (r >= 0 && r < TT) ? lse[b * TT + r] : 0.f;
    }
    __syncthreads();
    for (int idx = tid; idx < 12 * CC; idx += 256) {
        int i = idx / CC, c = idx - (idx / CC) * CC;
        int r = t_base - 4 + i;
        float pv = 0.f, lv = 0.f;
        if (r >= 0 && r < TT) {
            float x = fr[((size_t)b * TT + r) * CC + c];
            lv = x - lse_s[i];
            pv = __expf(lv);
        }
        sp[i][c] = pv;
        slp[i][c] = lv;
    }
    __syncthreads();
    // wave w computes score for t = t_base + w using staged rows w..w+8
    int t = t_base + wave;
    float acc = 0.f;
    for (int idx = lane; idx < 4 * CC; idx += 64) {
        int i = idx / CC, c = idx - (idx / CC) * CC;
        acc += -2.f * sp[wave + i][c] * slp[wave + i][c];
    }
    for (int item = lane; item < 36 * CC; item += 64) {
        int pidx = item / CC, c = item - pidx * CC;
        int i = 0, rem = pidx;
        while (rem >= 8 - i) { rem -= 8 - i; ++i; }
        int j = i + 1 + rem;
        float wgt = ((i < 4) == (j < 4)) ? 1.f : -1.f;
        float pi = sp[wave + i][c], pj = sp[wave + j][c];
        float logm = __logf(0.5f * (pi + pj) + 1e-32f);
        acc -= wgt * (pi + pj) * logm;
    }
    acc = wave_reduce_sum(acc);
    if (lane == 0) {
        const float SC = -2.0f / (81.0f * 0.6931471805599453f);
        score[(size_t)b * TT + t] = (t == 0) ? -INFINITY : SC * acc;
    }
}

// ---------------- Kernel 3: greedy pick, single wave, register-resident ----------------
__global__ __launch_bounds__(64) void k_pick(const float* __restrict__ score,
                                             int* __restrict__ cand,
                                             float* __restrict__ backup) {
    int b = blockIdx.x;
    int lane = threadIdx.x;
    __shared__ float s[64 * 33];
    __shared__ int cl[NCAND];
    for (int t = lane; t < TT; t += 64) s[t + (t >> 5)] = score[(size_t)b * TT + t];
    __syncthreads();
    float v[32];
    #pragma unroll
    for (int k = 0; k < 32; ++k) v[k] = s[lane * 33 + k];   // stride-33: conflict-free
    int base = lane << 5;
    for (int it = 0; it < NCAND; ++it) {
        // in-lane argmax, first index wins ties (descending k, >=)
        float best = -INFINITY; int bi = 0;
        #pragma unroll
        for (int k = 31; k >= 0; --k)
            if (v[k] >= best) { best = v[k]; bi = k; }
        // cross-lane max via DPP
        float m = best;
        m = DPPMAX(m, 0x111); m = DPPMAX(m, 0x112);
        m = DPPMAX(m, 0x114); m = DPPMAX(m, 0x118);
        m = DPPMAX(m, 0x142); m = DPPMAX(m, 0x143);
        float gmax = __int_as_float(__builtin_amdgcn_readlane(__float_as_int(m), 63));
        unsigned long long ball = __ballot(best == gmax);
        int sl = (int)(__ffsll((long long)ball) - 1);
        int mp = __builtin_amdgcn_readlane(base + bi, sl);
        if (lane == 0) cl[it] = mp;
        // suppress [mp-WINLEN, mp+WINLEN] in this lane's chunk via bitmask
        int llo = mp - WINLEN - base;
        int lhi = mp + WINLEN - base;
        unsigned lowm = (llo <= 0) ? 0xffffffffu : ((llo >= 32) ? 0u : ~((1u << llo) - 1u));
        unsigned him  = (lhi >= 31) ? 0xffffffffu : ((lhi < 0) ? 0u : ((2u << lhi) - 1u));
        unsigned wm = lowm & him;
        #pragma unroll
        for (int k = 0; k < 32; ++k)
            if (wm & (1u << k)) v[k] = -INFINITY;
    }
    __syncthreads();
    // rank-based parallel sort (positions distinct); backup from untouched LDS copy
    if (lane < NCAND) {
        int my = cl[lane];
        int rank = 0;
        for (int i = 0; i < NCAND; ++i) rank += (cl[i] < my) ? 1 : 0;
        cand[b * 64 + rank] = my;
        backup[b * 64 + rank] = s[my + (my >> 5)];
    }
}

// ---------------- Kernel 4: cls + DP + backtrack + rank + frCE + la-zero ----------------
__global__ __launch_bounds__(256) void k_dp(const float* __restrict__ fr,
                                            const float* __restrict__ lse,
                                            const int* __restrict__ cand,
                                            const float* __restrict__ backup,
                                            const int* __restrict__ transcript,
                                            int* __restrict__ labels_out,
                                            int* __restrict__ rowmap,
                                            float* __restrict__ fr_part,
                                            float* __restrict__ la) {
    int b = blockIdx.x;
    __shared__ float cost[NTR][NCAND];
    __shared__ int tr_s[LL];
    __shared__ int cand_s[NCAND];
    __shared__ float backup_s[NCAND];
    __shared__ signed char dir_mat[NCAND][32];
    __shared__ int bdy_s[NTR];
    __shared__ int rank_s[LL];
    __shared__ float redf[4];
    int tid = threadIdx.x;
    int wave = tid >> 6, lane = tid & 63;
    if (tid < LL) tr_s[tid] = transcript[b * LL + tid];
    if (tid < NCAND) {
        cand_s[tid] = cand[b * 64 + tid];
        backup_s[tid] = backup[b * 64 + tid];
    }

    // zero la for this batch (consumed later by k_la atomics)
    {
        float4 z = {0.f, 0.f, 0.f, 0.f};
        float4* lz = (float4*)(la + (size_t)b * LL * DD);
        #pragma unroll
        for (int i = 0; i < LL * DD / 4 / 256; ++i) lz[i * 256 + tid] = z;
    }
    __syncthreads();

    // ---- cls cost: p on the fly from fr/lse ----
    for (int e = tid; e < NTR * NCAND; e += 256) {
        int j = e / NCAND, ii = e - (e / NCAND) * NCAND;
        int cpos = cand_s[ii];
        int trj = tr_s[j], trj1 = tr_s[j + 1];
        float sum = 0.f;
        #pragma unroll
        for (int k = 0; k < CSW; ++k) {
            int r = cpos - CCHALF + k;
            float a = 0.f, d2 = 0.f;
            if (r >= 0 && r < TT) {
                size_t ro = (size_t)b * TT + r;
                float ls = lse[ro];
                a  = __expf(fr[ro * CC + trj]  - ls);
                d2 = __expf(fr[ro * CC + trj1] - ls);
            }
            sum += ((k < CCHALF) ? 1.f : -1.f) * (a - d2);
        }
        cost[j][ii] = -(sum / 30.f + backup_s[ii]);
    }
    __syncthreads();

    // ---- DP (wave 0, state j = lane j, W=31) ----
    if (tid < 64) {
        float prev = INFINITY;
        if (tid == 0) prev = 0.f;
        if (tid == 1) prev = cost[0][0];
        if (tid < 31) dir_mat[0][tid] = (tid == 1) ? (signed char)1 : (signed char)0;
        for (int ii = 1; ii < NCAND; ++ii) {
            float dm1 = __shfl_up(prev, 1); if (tid < 1) dm1 = INFINITY;
            float dm2 = __shfl_up(prev, 2); if (tid < 2) dm2 = INFINITY;
            int trat = tid >> 1; if (trat > NTR - 1) trat = NTR - 1;
            float c_at = cost[trat][ii];
            float ev = fminf(prev, dm1);
            int ed = (prev < dm1) ? 0 : 1;
            float ov = c_at + fminf(dm1, dm2);
            int od = (dm1 < dm2) ? 1 : 2;
            float nv; int nd;
            if (tid >= 2) {
                if ((tid & 1) == 0) { nv = ev; nd = ed; }
                else { nv = ov; nd = od; }
            } else { nv = INFINITY; nd = 0; }
            if (tid == 0) { nv = (ii < NCAND - NTR) ? 0.f : INFINITY; nd = 0; }
            if (tid == 1) {
                nv = (ii <= NCAND - NTR) ? cost[0][ii] : INFINITY;
                nd = (ii <= NCAND - NTR) ? 1 : 0;
            }
            prev = nv;
            if (tid < 31) dir_mat[ii][tid] = (signed char)nd;
        }
        float v29 = __shfl(prev, 29);
        float v30 = __shfl(prev, 30);
        if (tid == 0) {
            int cur = (v30 < v29) ? 30 : 29;
            for (int ii = NCAND - 1; ii >= 0; --ii) {
                if (cur & 1) bdy_s[cur >> 1] = cand_s[ii];
                cur -= (int)dir_mat[ii][cur];
            }
        }
    }
    __syncthreads();

    // ---- parallel rank (transcript values distinct) ----
    if (tid < LL) {
        int myv = tr_s[tid];
        int r2 = 0;
        #pragma unroll
        for (int l2 = 0; l2 < LL; ++l2) r2 += (tr_s[l2] < myv) ? 1 : 0;
        rank_s[tid] = r2;
        labels_out[b * LL + r2] = myv;   // sorted scatter
    }
    __syncthreads();

    // ---- fr CE partial + rowmap (pse inline) ----
    float facc = 0.f;
    for (int t = tid; t < TT; t += 256) {
        int cnt = 0;
        #pragma unroll
        for (int j = 0; j < NTR; ++j) cnt += (t >= bdy_s[j]) ? 1 : 0;
        int pv = tr_s[cnt];
        rowmap[b * TT + t] = rank_s[cnt];
        size_t ro = (size_t)b * TT + t;
        facc += lse[ro] - fr[ro * CC + pv];
    }
    facc = wave_reduce_sum(facc);
    if (lane == 0) redf[wave] = facc;
    __syncthreads();
    if (tid == 0) fr_part[b] = redf[0] + redf[1] + redf[2] + redf[3];
}

// ---------------- Kernel 5: segment feature sums, tile-scatter (atomics) ----------------
__global__ __launch_bounds__(256) void k_la(const float* __restrict__ feat,
                                            const int* __restrict__ rowmap,
                                            float* __restrict__ la) {
    int b = blockIdx.y;
    int t0 = blockIdx.x * 32;
    int tid = threadIdx.x;
    const float* frf = feat + ((size_t)b * (CC + TT) + CC) * DD;
    __shared__ int rm[32];
    if (tid < 32) rm[tid] = rowmap[b * TT + t0 + tid];
    __syncthreads();
    float ax = 0.f, ay = 0.f;
    int cur = rm[0];
    for (int k = 0; k < 32; ++k) {
        int r = rm[k];
        if (r != cur) {   // block-uniform branch
            float* dst = la + ((size_t)b * LL + cur) * DD + tid * 2;
            atomicAdd(dst, ax);
            atomicAdd(dst + 1, ay);
            ax = 0.f; ay = 0.f; cur = r;
        }
        const float2* p = (const float2*)(frf + (size_t)(t0 + k) * DD);
        float2 v = p[tid];
        ax += v.x; ay += v.y;
    }
    float* dst = la + ((size_t)b * LL + cur) * DD + tid * 2;
    atomicAdd(dst, ax);
    atomicAdd(dst + 1, ay);
}

// ---------------- Kernel 6: glc dots per (b,c): tok row staged, 16 dots + ntk ----------------
__global__ __launch_bounds__(256) void k_glc(const float* __restrict__ feat,
                                             const float* __restrict__ la,
                                             float* __restrict__ dots,
                                             float* __restrict__ ntk) {
    int c = blockIdx.x, b = blockIdx.y;
    __shared__ float tok_s[DD];
    __shared__ float redv[4];
    int tid = threadIdx.x;
    int wave = tid >> 6, lane = tid & 63;
    const float* tr = feat + ((size_t)b * (CC + TT) + c) * DD;
    float2 tv = ((const float2*)tr)[tid];
    ((float2*)tok_s)[tid] = tv;
    float vv = tv.x * tv.x + tv.y * tv.y;
    vv = wave_reduce_sum(vv);
    if (lane == 0) redv[wave] = vv;
    __syncthreads();
    if (tid == 0)
        ntk[b * CC + c] = fmaxf(sqrtf(redv[0] + redv[1] + redv[2] + redv[3]), 1e-12f);
    for (int l = wave; l < LL; l += 4) {
        const float4* lar = (const float4*)(la + ((size_t)b * LL + l) * DD);
        const float4* ts = (const float4*)tok_s;
        float dot = 0.f;
        #pragma unroll
        for (int jj = 0; jj < 2; ++jj) {
            int j = lane + jj * 64;
            float4 a = lar[j]; float4 w = ts[j];
            dot += a.x * w.x + a.y * w.y + a.z * w.z + a.w * w.w;
        }
        dot = wave_reduce_sum(dot);
        if (lane == 0) dots[((size_t)b * LL + l) * CC + c] = dot;
    }
}

// ---------------- Kernel 7: per-(b,l) term: nla + logsumexp ----------------
__global__ __launch_bounds__(64) void k_term(const float* __restrict__ la,
                                             const float* __restrict__ dots,
                                             const float* __restrict__ ntk,
                                             const int* __restrict__ labels,
                                             float* __restrict__ terms) {
    int l = blockIdx.x, b = blockIdx.y;
    int lane = threadIdx.x;
    const float4* lar = (const float4*)(la + ((size_t)b * LL + l) * DD);
    float ss = 0.f;
    #pragma unroll
    for (int jj = 0; jj < 2; ++jj) {
        float4 a = lar[lane + jj * 64];
        ss += a.x * a.x + a.y * a.y + a.z * a.z + a.w * a.w;
    }
    ss = wave_reduce_sum(ss);
    float nla = fmaxf(sqrtf(__shfl(ss, 0)), 1e-12f);
    float sim = -INFINITY;
    if (lane < CC)
        sim = dots[((size_t)b * LL + l) * CC + lane] * 10.0f / (nla * ntk[b * CC + lane]);
    float mx = sim;
    for (int off = 32; off; off >>= 1) mx = fmaxf(mx, __shfl_down(mx, off));
    mx = __shfl(mx, 0);
    float e = (lane < CC) ? expf(sim - mx) : 0.f;
    float se = wave_reduce_sum(e);
    se = __shfl(se, 0);
    int lab = labels[b * LL + l];
    float sim_lab = __shfl(sim, lab);
    if (lane == 0) terms[b * LL + l] = (mx + logf(se)) - sim_lab;
}

// ---------------- Kernel 8: combine ----------------
__global__ __launch_bounds__(256) void k_combine(const float* __restrict__ tok_logit,
                                                 const float* __restrict__ vid,
                                                 const float* __restrict__ fr_part,
                                                 const float* __restrict__ terms,
                                                 float* __restrict__ out) {
    int tid = threadIdx.x;
    __shared__ float red[4];
    __shared__ float gterm;
    float acc = 0.f;
    if (tid < BB * CC) {
        float x = tok_logit[tid], y = vid[tid];
        float lsp = fminf(x, 0.f) - log1pf(expf(-fabsf(x)));
        float lsn = fminf(-x, 0.f) - log1pf(expf(-fabsf(x)));
        acc = -(y * lsp + (1.f - y) * lsn);
    }
    float w = wave_reduce_sum(acc);
    if ((tid & 63) == 0) red[tid >> 6] = w;
    // wave 0: glc terms (64 values)
    if (tid < 64) {
        float g = terms[tid];
        g = wave_reduce_sum(g);
        if (tid == 0) gterm = g;
    }
    __syncthreads();
    if (tid == 0) {
        float s_tok = (red[0] + red[1] + red[2] + red[3]) / (float)(BB * CC);
        float sfr = fr_part[0] + fr_part[1] + fr_part[2] + fr_part[3];
        float s_fr = sfr / (float)(BB * TT);
        float glc = gterm / (float)(BB * LL);
        out[0] = s_tok + s_fr + 0.1f * glc;
    }
}

extern "C" void kernel_launch(void* const* d_in, const int* in_sizes, int n_in,
                              void* d_out, int out_size, void* d_ws, size_t ws_size,
                              hipStream_t stream) {
    (void)in_sizes; (void)n_in; (void)out_size; (void)ws_size;
    // input order: epoch, tok_logit, fr_logit, mask, transcript, vid_multi_hot, feat
    const float* tok_logit  = (const float*)d_in[1];
    const float* fr_logit   = (const float*)d_in[2];
    const int*   transcript = (const int*)d_in[4];
    const float* vid        = (const float*)d_in[5];
    const float* feat       = (const float*)d_in[6];

    char* ws = (char*)d_ws;
    float* lse     = (float*)(ws + 0);        // B*T (32768 B)
    float* score   = (float*)(ws + 32768);    // B*T (32768 B)
    float* la      = (float*)(ws + 65536);    // B*L*D (131072 B)
    float* dots    = (float*)(ws + 196608);   // B*L*C (12288 B)
    float* ntk     = (float*)(ws + 208896);   // B*C
    float* terms   = (float*)(ws + 209664);   // B*L
    float* fr_part = (float*)(ws + 209920);   // 4
    int*   labels  = (int*)(ws + 210176);     // B*L
    int*   rowmap  = (int*)(ws + 210432);     // B*T (32768 B)
    int*   cand    = (int*)(ws + 243200);     // B*64
    float* backup  = (float*)(ws + 244224);   // B*64
    float* out     = (float*)d_out;

    k_lse<<<BB * TT / 4, 256, 0, stream>>>(fr_logit, lse);
    k_score<<<BB * TT / 4, 256, 0, stream>>>(fr_logit, lse, score);
    k_pick<<<BB, 64, 0, stream>>>(score, cand, backup);
    k_dp<<<BB, 256, 0, stream>>>(fr_logit, lse, cand, backup, transcript,
                                 labels, rowmap, fr_part, la);
    k_la<<<dim3(TT / 32, BB), 256, 0, stream>>>(feat, rowmap, la);
    k_glc<<<dim3(CC, BB), 256, 0, stream>>>(feat, la, dots, ntk);
    k_term<<<dim3(LL, BB), 64, 0, stream>>>(la, dots, ntk, labels, terms);
    k_combine<<<1, 256, 0, stream>>>(tok_logit, vid, fr_part, terms, out);
}

// Round 13
// 164.656 us; speedup vs baseline: 1.2373x; 1.0484x over previous
//
#include <hip/hip_runtime.h>
#include <math.h>

// Problem constants (from reference)
#define BB 4
#define TT 2048
#define CC 48
#define DD 512
#define LL 16
#define NTR 15
#define NCAND 45
#define WINLEN 19   // int(T/L*0.15)
#define CSW 15
#define CCHALF 7

static __device__ __forceinline__ float wave_reduce_sum(float v) {
    for (int off = 32; off; off >>= 1) v += __shfl_down(v, off);
    return v;
}

// DPP max step
#define DPPMAX(x, ctrl) fmaxf((x), __int_as_float(__builtin_amdgcn_update_dpp( \
    __float_as_int(x), __float_as_int(x), (ctrl), 0xF, 0xF, false)))

// ---------------- Kernel 1: row log-sum-exp only ----------------
__global__ __launch_bounds__(256) void k_lse(const float* __restrict__ fr,
                                             float* __restrict__ lse) {
    int row = blockIdx.x * 4 + (threadIdx.x >> 6);   // 4 rows/block
    int lane = threadIdx.x & 63;
    float xv = (lane < CC) ? fr[(size_t)row * CC + lane] : -INFINITY;
    float m = xv;
    for (int off = 32; off; off >>= 1) m = fmaxf(m, __shfl_down(m, off));
    m = __shfl(m, 0);
    float e = (lane < CC) ? __expf(xv - m) : 0.f;
    float s = wave_reduce_sum(e);
    if (lane == 0) lse[row] = m + __logf(s);
}

// ---------------- Kernel 2: boundary (JS) score, 4 t's/block (shared staging) ----------------
__global__ __launch_bounds__(256) void k_score(const float* __restrict__ fr,
                                               const float* __restrict__ lse,
                                               float* __restrict__ score) {
    int t_base = (blockIdx.x * 4) % TT;
    int b = (blockIdx.x * 4) / TT;
    __shared__ float sp[12][CC];
    __shared__ float slp[12][CC];
    __shared__ float lse_s[12];
    int tid = threadIdx.x;
    int wave = tid >> 6, lane = tid & 63;
    if (tid < 12) {
        int r = t_base - 4 + tid;
        lse_s[tid] = (r >= 0 && r < TT) ? lse[b * TT + r] : 0.f;
    }
    __syncthreads();
    for (int idx = tid; idx < 12 * CC; idx += 256) {
        int i = idx / CC, c = idx - (idx / CC) * CC;
        int r = t_base - 4 + i;
        float pv = 0.f, lv = 0.f;
        if (r >= 0 && r < TT) {
            float x = fr[((size_t)b * TT + r) * CC + c];
            lv = x - lse_s[i];
            pv = __expf(lv);
        }
        sp[i][c] = pv;
        slp[i][c] = lv;
    }
    __syncthreads();
    int t = t_base + wave;
    float acc = 0.f;
    for (int idx = lane; idx < 4 * CC; idx += 64) {
        int i = idx / CC, c = idx - (idx / CC) * CC;
        acc += -2.f * sp[wave + i][c] * slp[wave + i][c];
    }
    for (int item = lane; item < 36 * CC; item += 64) {
        int pidx = item / CC, c = item - pidx * CC;
        int i = 0, rem = pidx;
        while (rem >= 8 - i) { rem -= 8 - i; ++i; }
        int j = i + 1 + rem;
        float wgt = ((i < 4) == (j < 4)) ? 1.f : -1.f;
        float pi = sp[wave + i][c], pj = sp[wave + j][c];
        float logm = __logf(0.5f * (pi + pj) + 1e-32f);
        acc -= wgt * (pi + pj) * logm;
    }
    acc = wave_reduce_sum(acc);
    if (lane == 0) {
        const float SC = -2.0f / (81.0f * 0.6931471805599453f);
        score[(size_t)b * TT + t] = (t == 0) ? -INFINITY : SC * acc;
    }
}

// ---------------- Kernel 3: greedy pick, single wave, register-resident ----------------
__global__ __launch_bounds__(64) void k_pick(const float* __restrict__ score,
                                             int* __restrict__ cand,
                                             float* __restrict__ backup) {
    int b = blockIdx.x;
    int lane = threadIdx.x;
    __shared__ float s[64 * 33];
    __shared__ int cl[NCAND];
    for (int t = lane; t < TT; t += 64) s[t + (t >> 5)] = score[(size_t)b * TT + t];
    __syncthreads();
    float v[32];
    #pragma unroll
    for (int k = 0; k < 32; ++k) v[k] = s[lane * 33 + k];   // stride-33: conflict-free
    int base = lane << 5;
    for (int it = 0; it < NCAND; ++it) {
        float best = -INFINITY; int bi = 0;
        #pragma unroll
        for (int k = 31; k >= 0; --k)
            if (v[k] >= best) { best = v[k]; bi = k; }
        float m = best;
        m = DPPMAX(m, 0x111); m = DPPMAX(m, 0x112);
        m = DPPMAX(m, 0x114); m = DPPMAX(m, 0x118);
        m = DPPMAX(m, 0x142); m = DPPMAX(m, 0x143);
        float gmax = __int_as_float(__builtin_amdgcn_readlane(__float_as_int(m), 63));
        unsigned long long ball = __ballot(best == gmax);
        int sl = (int)(__ffsll((long long)ball) - 1);
        int mp = __builtin_amdgcn_readlane(base + bi, sl);
        if (lane == 0) cl[it] = mp;
        int llo = mp - WINLEN - base;
        int lhi = mp + WINLEN - base;
        unsigned lowm = (llo <= 0) ? 0xffffffffu : ((llo >= 32) ? 0u : ~((1u << llo) - 1u));
        unsigned him  = (lhi >= 31) ? 0xffffffffu : ((lhi < 0) ? 0u : ((2u << lhi) - 1u));
        unsigned wm = lowm & him;
        #pragma unroll
        for (int k = 0; k < 32; ++k)
            if (wm & (1u << k)) v[k] = -INFINITY;
    }
    __syncthreads();
    if (lane < NCAND) {
        int my = cl[lane];
        int rank = 0;
        for (int i = 0; i < NCAND; ++i) rank += (cl[i] < my) ? 1 : 0;
        cand[b * 64 + rank] = my;
        backup[b * 64 + rank] = s[my + (my >> 5)];
    }
}

// ---------------- Kernel 4: cls cost, one block per (candidate, batch) ----------------
// 180 blocks; each stages its candidate's 15x16 window of softmax-p (one load/thread,
// single round) and emits one cost column. Removes the 4-block gather from k_dp.
__global__ __launch_bounds__(256) void k_cls(const float* __restrict__ fr,
                                             const float* __restrict__ lse,
                                             const int* __restrict__ cand,
                                             const float* __restrict__ backup,
                                             const int* __restrict__ transcript,
                                             float* __restrict__ cost_g) {
    int ii = blockIdx.x, b = blockIdx.y;
    __shared__ float win[CSW][LL + 1];
    __shared__ int tr_s[LL];
    int tid = threadIdx.x;
    if (tid < LL) tr_s[tid] = transcript[b * LL + tid];
    __syncthreads();
    int cpos = cand[b * 64 + ii];
    if (tid < CSW * LL) {
        int k = tid >> 4, m2 = tid & 15;
        int r = cpos - CCHALF + k;
        float p = 0.f;
        if (r >= 0 && r < TT) {
            size_t ro = (size_t)b * TT + r;
            p = __expf(fr[ro * CC + tr_s[m2]] - lse[ro]);
        }
        win[k][m2] = p;
    }
    __syncthreads();
    if (tid < NTR) {
        int j = tid;
        float sum = 0.f;
        #pragma unroll
        for (int k = 0; k < CSW; ++k)
            sum += ((k < CCHALF) ? 1.f : -1.f) * (win[k][j] - win[k][j + 1]);
        cost_g[(b * NTR + j) * NCAND + ii] = -(sum / 30.f + backup[b * 64 + ii]);
    }
}

// ---------------- Kernel 5: DP + backtrack + rank + frCE + la-zero ----------------
__global__ __launch_bounds__(256) void k_dp(const float* __restrict__ fr,
                                            const float* __restrict__ lse,
                                            const int* __restrict__ cand,
                                            const float* __restrict__ cost_g,
                                            const int* __restrict__ transcript,
                                            int* __restrict__ labels_out,
                                            int* __restrict__ rowmap,
                                            float* __restrict__ fr_part,
                                            float* __restrict__ la) {
    int b = blockIdx.x;
    __shared__ float cost[NTR][NCAND];
    __shared__ int tr_s[LL];
    __shared__ int cand_s[NCAND];
    __shared__ signed char dir_mat[NCAND][32];
    __shared__ int bdy_s[NTR];
    __shared__ int rank_s[LL];
    __shared__ float redf[4];
    int tid = threadIdx.x;
    int wave = tid >> 6, lane = tid & 63;
    if (tid < LL) tr_s[tid] = transcript[b * LL + tid];
    if (tid < NCAND) cand_s[tid] = cand[b * 64 + tid];

    // zero la for this batch (consumed later by k_la atomics)
    {
        float4 z = {0.f, 0.f, 0.f, 0.f};
        float4* lz = (float4*)(la + (size_t)b * LL * DD);
        #pragma unroll
        for (int i = 0; i < LL * DD / 4 / 256; ++i) lz[i * 256 + tid] = z;
    }
    // load precomputed cost matrix (675 floats)
    for (int e = tid; e < NTR * NCAND; e += 256) {
        int j = e / NCAND, ii = e - j * NCAND;
        cost[j][ii] = cost_g[b * NTR * NCAND + e];
    }
    __syncthreads();

    // ---- DP (wave 0, state j = lane j, W=31) ----
    if (tid < 64) {
        float prev = INFINITY;
        if (tid == 0) prev = 0.f;
        if (tid == 1) prev = cost[0][0];
        if (tid < 31) dir_mat[0][tid] = (tid == 1) ? (signed char)1 : (signed char)0;
        for (int ii = 1; ii < NCAND; ++ii) {
            float dm1 = __shfl_up(prev, 1); if (tid < 1) dm1 = INFINITY;
            float dm2 = __shfl_up(prev, 2); if (tid < 2) dm2 = INFINITY;
            int trat = tid >> 1; if (trat > NTR - 1) trat = NTR - 1;
            float c_at = cost[trat][ii];
            float ev = fminf(prev, dm1);
            int ed = (prev < dm1) ? 0 : 1;
            float ov = c_at + fminf(dm1, dm2);
            int od = (dm1 < dm2) ? 1 : 2;
            float nv; int nd;
            if (tid >= 2) {
                if ((tid & 1) == 0) { nv = ev; nd = ed; }
                else { nv = ov; nd = od; }
            } else { nv = INFINITY; nd = 0; }
            if (tid == 0) { nv = (ii < NCAND - NTR) ? 0.f : INFINITY; nd = 0; }
            if (tid == 1) {
                nv = (ii <= NCAND - NTR) ? cost[0][ii] : INFINITY;
                nd = (ii <= NCAND - NTR) ? 1 : 0;
            }
            prev = nv;
            if (tid < 31) dir_mat[ii][tid] = (signed char)nd;
        }
        float v29 = __shfl(prev, 29);
        float v30 = __shfl(prev, 30);
        if (tid == 0) {
            int cur = (v30 < v29) ? 30 : 29;
            for (int ii = NCAND - 1; ii >= 0; --ii) {
                if (cur & 1) bdy_s[cur >> 1] = cand_s[ii];
                cur -= (int)dir_mat[ii][cur];
            }
        }
    }
    __syncthreads();

    // ---- parallel rank (transcript values distinct) ----
    if (tid < LL) {
        int myv = tr_s[tid];
        int r2 = 0;
        #pragma unroll
        for (int l2 = 0; l2 < LL; ++l2) r2 += (tr_s[l2] < myv) ? 1 : 0;
        rank_s[tid] = r2;
        labels_out[b * LL + r2] = myv;   // sorted scatter
    }
    __syncthreads();

    // ---- fr CE partial + rowmap (pse inline) ----
    float facc = 0.f;
    for (int t = tid; t < TT; t += 256) {
        int cnt = 0;
        #pragma unroll
        for (int j = 0; j < NTR; ++j) cnt += (t >= bdy_s[j]) ? 1 : 0;
        int pv = tr_s[cnt];
        rowmap[b * TT + t] = rank_s[cnt];
        size_t ro = (size_t)b * TT + t;
        facc += lse[ro] - fr[ro * CC + pv];
    }
    facc = wave_reduce_sum(facc);
    if (lane == 0) redf[wave] = facc;
    __syncthreads();
    if (tid == 0) fr_part[b] = redf[0] + redf[1] + redf[2] + redf[3];
}

// ---------------- Kernel 6: segment feature sums, tile-scatter (atomics) ----------------
__global__ __launch_bounds__(256) void k_la(const float* __restrict__ feat,
                                            const int* __restrict__ rowmap,
                                            float* __restrict__ la) {
    int b = blockIdx.y;
    int t0 = blockIdx.x * 32;
    int tid = threadIdx.x;
    const float* frf = feat + ((size_t)b * (CC + TT) + CC) * DD;
    __shared__ int rm[32];
    if (tid < 32) rm[tid] = rowmap[b * TT + t0 + tid];
    __syncthreads();
    float ax = 0.f, ay = 0.f;
    int cur = rm[0];
    for (int k = 0; k < 32; ++k) {
        int r = rm[k];
        if (r != cur) {   // block-uniform branch
            float* dst = la + ((size_t)b * LL + cur) * DD + tid * 2;
            atomicAdd(dst, ax);
            atomicAdd(dst + 1, ay);
            ax = 0.f; ay = 0.f; cur = r;
        }
        const float2* p = (const float2*)(frf + (size_t)(t0 + k) * DD);
        float2 v = p[tid];
        ax += v.x; ay += v.y;
    }
    float* dst = la + ((size_t)b * LL + cur) * DD + tid * 2;
    atomicAdd(dst, ax);
    atomicAdd(dst + 1, ay);
}

// ---------------- Kernel 7: glc dots per (b,c): tok row staged, 16 dots + ntk ----------------
__global__ __launch_bounds__(256) void k_glc(const float* __restrict__ feat,
                                             const float* __restrict__ la,
                                             float* __restrict__ dots,
                                             float* __restrict__ ntk) {
    int c = blockIdx.x, b = blockIdx.y;
    __shared__ float tok_s[DD];
    __shared__ float redv[4];
    int tid = threadIdx.x;
    int wave = tid >> 6, lane = tid & 63;
    const float* tr = feat + ((size_t)b * (CC + TT) + c) * DD;
    float2 tv = ((const float2*)tr)[tid];
    ((float2*)tok_s)[tid] = tv;
    float vv = tv.x * tv.x + tv.y * tv.y;
    vv = wave_reduce_sum(vv);
    if (lane == 0) redv[wave] = vv;
    __syncthreads();
    if (tid == 0)
        ntk[b * CC + c] = fmaxf(sqrtf(redv[0] + redv[1] + redv[2] + redv[3]), 1e-12f);
    for (int l = wave; l < LL; l += 4) {
        const float4* lar = (const float4*)(la + ((size_t)b * LL + l) * DD);
        const float4* ts = (const float4*)tok_s;
        float dot = 0.f;
        #pragma unroll
        for (int jj = 0; jj < 2; ++jj) {
            int j = lane + jj * 64;
            float4 a = lar[j]; float4 w = ts[j];
            dot += a.x * w.x + a.y * w.y + a.z * w.z + a.w * w.w;
        }
        dot = wave_reduce_sum(dot);
        if (lane == 0) dots[((size_t)b * LL + l) * CC + c] = dot;
    }
}

// ---------------- Kernel 8: per-(b,l) term: nla + logsumexp ----------------
__global__ __launch_bounds__(64) void k_term(const float* __restrict__ la,
                                             const float* __restrict__ dots,
                                             const float* __restrict__ ntk,
                                             const int* __restrict__ labels,
                                             float* __restrict__ terms) {
    int l = blockIdx.x, b = blockIdx.y;
    int lane = threadIdx.x;
    const float4* lar = (const float4*)(la + ((size_t)b * LL + l) * DD);
    float ss = 0.f;
    #pragma unroll
    for (int jj = 0; jj < 2; ++jj) {
        float4 a = lar[lane + jj * 64];
        ss += a.x * a.x + a.y * a.y + a.z * a.z + a.w * a.w;
    }
    ss = wave_reduce_sum(ss);
    float nla = fmaxf(sqrtf(__shfl(ss, 0)), 1e-12f);
    float sim = -INFINITY;
    if (lane < CC)
        sim = dots[((size_t)b * LL + l) * CC + lane] * 10.0f / (nla * ntk[b * CC + lane]);
    float mx = sim;
    for (int off = 32; off; off >>= 1) mx = fmaxf(mx, __shfl_down(mx, off));
    mx = __shfl(mx, 0);
    float e = (lane < CC) ? expf(sim - mx) : 0.f;
    float se = wave_reduce_sum(e);
    se = __shfl(se, 0);
    int lab = labels[b * LL + l];
    float sim_lab = __shfl(sim, lab);
    if (lane == 0) terms[b * LL + l] = (mx + logf(se)) - sim_lab;
}

// ---------------- Kernel 9: combine ----------------
__global__ __launch_bounds__(256) void k_combine(const float* __restrict__ tok_logit,
                                                 const float* __restrict__ vid,
                                                 const float* __restrict__ fr_part,
                                                 const float* __restrict__ terms,
                                                 float* __restrict__ out) {
    int tid = threadIdx.x;
    __shared__ float red[4];
    __shared__ float gterm;
    float acc = 0.f;
    if (tid < BB * CC) {
        float x = tok_logit[tid], y = vid[tid];
        float lsp = fminf(x, 0.f) - log1pf(expf(-fabsf(x)));
        float lsn = fminf(-x, 0.f) - log1pf(expf(-fabsf(x)));
        acc = -(y * lsp + (1.f - y) * lsn);
    }
    float w = wave_reduce_sum(acc);
    if ((tid & 63) == 0) red[tid >> 6] = w;
    if (tid < 64) {
        float g = terms[tid];
        g = wave_reduce_sum(g);
        if (tid == 0) gterm = g;
    }
    __syncthreads();
    if (tid == 0) {
        float s_tok = (red[0] + red[1] + red[2] + red[3]) / (float)(BB * CC);
        float sfr = fr_part[0] + fr_part[1] + fr_part[2] + fr_part[3];
        float s_fr = sfr / (float)(BB * TT);
        float glc = gterm / (float)(BB * LL);
        out[0] = s_tok + s_fr + 0.1f * glc;
    }
}

extern "C" void kernel_launch(void* const* d_in, const int* in_sizes, int n_in,
                              void* d_out, int out_size, void* d_ws, size_t ws_size,
                              hipStream_t stream) {
    (void)in_sizes; (void)n_in; (void)out_size; (void)ws_size;
    // input order: epoch, tok_logit, fr_logit, mask, transcript, vid_multi_hot, feat
    const float* tok_logit  = (const float*)d_in[1];
    const float* fr_logit   = (const float*)d_in[2];
    const int*   transcript = (const int*)d_in[4];
    const float* vid        = (const float*)d_in[5];
    const float* feat       = (const float*)d_in[6];

    char* ws = (char*)d_ws;
    float* lse     = (float*)(ws + 0);        // B*T (32768 B)
    float* score   = (float*)(ws + 32768);    // B*T (32768 B)
    float* la      = (float*)(ws + 65536);    // B*L*D (131072 B)
    float* dots    = (float*)(ws + 196608);   // B*L*C (12288 B)
    float* ntk     = (float*)(ws + 208896);   // B*C
    float* terms   = (float*)(ws + 209664);   // B*L
    float* fr_part = (float*)(ws + 209920);   // 4
    int*   labels  = (int*)(ws + 210176);     // B*L
    int*   rowmap  = (int*)(ws + 210432);     // B*T (32768 B)
    int*   cand    = (int*)(ws + 243200);     // B*64
    float* backup  = (float*)(ws + 244224);   // B*64
    float* cost_g  = (float*)(ws + 245248);   // B*NTR*NCAND (10800 B)
    float* out     = (float*)d_out;

    k_lse<<<BB * TT / 4, 256, 0, stream>>>(fr_logit, lse);
    k_score<<<BB * TT / 4, 256, 0, stream>>>(fr_logit, lse, score);
    k_pick<<<BB, 64, 0, stream>>>(score, cand, backup);
    k_cls<<<dim3(NCAND, BB), 256, 0, stream>>>(fr_logit, lse, cand, backup,
                                               transcript, cost_g);
    k_dp<<<BB, 256, 0, stream>>>(fr_logit, lse, cand, cost_g, transcript,
                                 labels, rowmap, fr_part, la);
    k_la<<<dim3(TT / 32, BB), 256, 0, stream>>>(feat, rowmap, la);
    k_glc<<<dim3(CC, BB), 256, 0, stream>>>(feat, la, dots, ntk);
    k_term<<<dim3(LL, BB), 64, 0, stream>>>(la, dots, ntk, labels, terms);
    k_combine<<<1, 256, 0, stream>>>(tok_logit, vid, fr_part, terms, out);
}